// Round 1
// baseline (595.482 us; speedup 1.0000x reference)
//
#include <hip/hip_runtime.h>

// Problem: ExodusModel_8564164788248
// inp: (8,2,256,256,64) f32, w0: (4,2,7,7), w1: (8,4,7,7), wl: (2,128)
// out: (8,2,64) f32
//
// Workspace layout (floats):
//   pooled0 : (8,2,64,64,64)  = 4,194,304   @ 0
//   h0/s0   : (8,4,64,64,64)  = 8,388,608   @ 4,194,304
//   pooled1 : (8,4,16,16,64)  =   524,288   @ 12,582,912
//   h1/s1   : (8,8,16,16,64)  = 1,048,576   @ 13,107,200
//   total 14,155,776 floats = 56.6 MB

#define OFF_P0   0
#define OFF_H0   4194304
#define OFF_P1   12582912
#define OFF_H1   13107200

// ---------------------------------------------------------------------------
// K1: avgpool 4x4 on raw input. (n,c,256,256,t) -> (n,c,64,64,t)
// lane = t (stride-1) => fully coalesced. fp64 accumulate (exact /16).
__global__ void pool0_kernel(const float* __restrict__ inp,
                             float* __restrict__ out) {
    int tid = blockIdx.x * blockDim.x + threadIdx.x;   // 4,194,304 threads
    int t  = tid & 63;
    int px = (tid >> 6) & 63;
    int py = (tid >> 12) & 63;
    int nc = tid >> 18;                                // n*2+c, 0..15
    const float* base = inp + (size_t)nc * 256 * 256 * 64;
    int y0 = py * 4, x0 = px * 4;
    double s = 0.0;
    #pragma unroll
    for (int dy = 0; dy < 4; ++dy) {
        const float* row = base + ((size_t)(y0 + dy) * 256 + x0) * 64 + t;
        #pragma unroll
        for (int dx = 0; dx < 4; ++dx)
            s += (double)row[dx * 64];
    }
    out[tid] = (float)(s * 0.0625);   // output flat idx == tid by construction
}

// ---------------------------------------------------------------------------
// K2: conv7 pad3, ic=2 -> oc=4 on (n,2,64,64,t). One thread per (n,py,px,t),
// computes all 4 oc (tap loaded once, 4 FMAs). fp64 accumulate.
__global__ void conv0_kernel(const float* __restrict__ pooled0,
                             const float* __restrict__ w0,
                             float* __restrict__ h0) {
    __shared__ double w[392];                          // (4,2,7,7)
    for (int i = threadIdx.x; i < 392; i += blockDim.x) w[i] = (double)w0[i];
    __syncthreads();

    int tid = blockIdx.x * blockDim.x + threadIdx.x;   // 2,097,152 threads
    int t  = tid & 63;
    int px = (tid >> 6) & 63;
    int py = (tid >> 12) & 63;
    int n  = tid >> 18;                                // 0..7
    double acc0 = 0, acc1 = 0, acc2 = 0, acc3 = 0;
    for (int ic = 0; ic < 2; ++ic) {
        const float* in_c = pooled0 + (size_t)(n * 2 + ic) * 64 * 64 * 64;
        const double* wic = w + ic * 49;               // + oc*98 + ky*7 + kx
        #pragma unroll
        for (int ky = 0; ky < 7; ++ky) {
            int iy = py + ky - 3;
            if (iy < 0 || iy >= 64) continue;
            const float* in_row = in_c + (size_t)iy * 64 * 64 + t;
            const double* wrow = wic + ky * 7;
            #pragma unroll
            for (int kx = 0; kx < 7; ++kx) {
                int ix = px + kx - 3;
                if (ix < 0 || ix >= 64) continue;
                double v = (double)in_row[ix * 64];
                acc0 += v * wrow[kx];
                acc1 += v * wrow[kx + 98];
                acc2 += v * wrow[kx + 196];
                acc3 += v * wrow[kx + 294];
            }
        }
    }
    size_t ob = (size_t)n * 4 * 262144 + (size_t)py * 4096 + px * 64 + t;
    h0[ob]          = (float)acc0;
    h0[ob + 262144] = (float)acc1;
    h0[ob + 524288] = (float)acc2;
    h0[ob + 786432] = (float)acc3;
}

// ---------------------------------------------------------------------------
// K3/K5: IAF (MembraneSubtract) in-place over 64 contiguous timesteps.
// fp32 membrane, EXACT op sequence of the reference: v+=x; s=(v>=1); v-=s.
__global__ void iaf_kernel(float* __restrict__ buf) {
    int tid = blockIdx.x * blockDim.x + threadIdx.x;   // one thread / position
    float4* p = (float4*)(buf + (size_t)tid * 64);
    float v = 0.0f;
    #pragma unroll
    for (int i = 0; i < 16; ++i) {
        float4 x = p[i];
        v += x.x; { float s = (v >= 1.0f) ? 1.0f : 0.0f; v -= s; x.x = s; }
        v += x.y; { float s = (v >= 1.0f) ? 1.0f : 0.0f; v -= s; x.y = s; }
        v += x.z; { float s = (v >= 1.0f) ? 1.0f : 0.0f; v -= s; x.z = s; }
        v += x.w; { float s = (v >= 1.0f) ? 1.0f : 0.0f; v -= s; x.w = s; }
        p[i] = x;
    }
}

// ---------------------------------------------------------------------------
// K4a: avgpool 4x4 on spikes (8,4,64,64,t) -> (8,4,16,16,t). Exact in fp32.
__global__ void pool1_kernel(const float* __restrict__ s0,
                             float* __restrict__ out) {
    int tid = blockIdx.x * blockDim.x + threadIdx.x;   // 524,288 threads
    int t  = tid & 63;
    int px = (tid >> 6) & 15;
    int py = (tid >> 10) & 15;
    int nc = tid >> 14;                                // n*4+c, 0..31
    const float* base = s0 + (size_t)nc * 64 * 64 * 64;
    int y0 = py * 4, x0 = px * 4;
    float s = 0.0f;
    #pragma unroll
    for (int dy = 0; dy < 4; ++dy) {
        const float* row = base + ((size_t)(y0 + dy) * 64 + x0) * 64 + t;
        #pragma unroll
        for (int dx = 0; dx < 4; ++dx)
            s += row[dx * 64];
    }
    out[tid] = s * 0.0625f;
}

// ---------------------------------------------------------------------------
// K4b: conv7 pad3, ic=4 -> oc=8 on (8,4,16,16,t). fp64 accumulate.
__global__ void conv1_kernel(const float* __restrict__ pooled1,
                             const float* __restrict__ w1,
                             float* __restrict__ h1) {
    __shared__ double w[1568];                         // (8,4,7,7)
    for (int i = threadIdx.x; i < 1568; i += blockDim.x) w[i] = (double)w1[i];
    __syncthreads();

    int tid = blockIdx.x * blockDim.x + threadIdx.x;   // 131,072 threads
    int t  = tid & 63;
    int px = (tid >> 6) & 15;
    int py = (tid >> 10) & 15;
    int n  = tid >> 14;                                // 0..7
    double acc[8];
    #pragma unroll
    for (int oc = 0; oc < 8; ++oc) acc[oc] = 0.0;

    for (int ic = 0; ic < 4; ++ic) {
        const float* in_c = pooled1 + (size_t)(n * 4 + ic) * 16 * 16 * 64;
        const double* wic = w + ic * 49;               // + oc*196 + ky*7 + kx
        #pragma unroll
        for (int ky = 0; ky < 7; ++ky) {
            int iy = py + ky - 3;
            if (iy < 0 || iy >= 16) continue;
            const float* in_row = in_c + (size_t)iy * 16 * 64 + t;
            const double* wrow = wic + ky * 7;
            #pragma unroll
            for (int kx = 0; kx < 7; ++kx) {
                int ix = px + kx - 3;
                if (ix < 0 || ix >= 16) continue;
                double v = (double)in_row[ix * 64];
                #pragma unroll
                for (int oc = 0; oc < 8; ++oc)
                    acc[oc] += v * wrow[kx + oc * 196];
            }
        }
    }
    size_t ob = (size_t)n * 8 * 16384 + (size_t)py * 1024 + px * 64 + t;
    #pragma unroll
    for (int oc = 0; oc < 8; ++oc)
        h1[ob + (size_t)oc * 16384] = (float)acc[oc];
}

// ---------------------------------------------------------------------------
// K6: avgpool4 (16x16 -> 4x4) + flatten(128) + linear (wl: (2,128)).
// out: (8,2,64). Spike sums exact; dot in fp64.
__global__ void final_kernel(const float* __restrict__ s1,
                             const float* __restrict__ wl,
                             float* __restrict__ out) {
    int tid = blockIdx.x * blockDim.x + threadIdx.x;   // 1024 threads
    int t = tid & 63;
    int j = (tid >> 6) & 1;
    int n = tid >> 7;
    double acc = 0.0;
    for (int c = 0; c < 8; ++c) {
        const float* base = s1 + (size_t)(n * 8 + c) * 16 * 16 * 64;
        #pragma unroll
        for (int py = 0; py < 4; ++py) {
            #pragma unroll
            for (int px = 0; px < 4; ++px) {
                float ssum = 0.0f;
                #pragma unroll
                for (int dy = 0; dy < 4; ++dy) {
                    const float* row = base + ((size_t)(py * 4 + dy) * 16 + px * 4) * 64 + t;
                    #pragma unroll
                    for (int dx = 0; dx < 4; ++dx)
                        ssum += row[dx * 64];
                }
                float feat = ssum * 0.0625f;
                acc += (double)wl[j * 128 + c * 16 + py * 4 + px] * (double)feat;
            }
        }
    }
    out[(size_t)(n * 2 + j) * 64 + t] = (float)acc;
}

// ---------------------------------------------------------------------------
extern "C" void kernel_launch(void* const* d_in, const int* in_sizes, int n_in,
                              void* d_out, int out_size, void* d_ws, size_t ws_size,
                              hipStream_t stream) {
    const float* inp = (const float*)d_in[0];
    const float* w0  = (const float*)d_in[1];
    const float* w1  = (const float*)d_in[2];
    const float* wl  = (const float*)d_in[3];
    float* out = (float*)d_out;
    float* ws  = (float*)d_ws;

    float* pooled0 = ws + OFF_P0;
    float* h0      = ws + OFF_H0;   // becomes s0 in-place after iaf
    float* pooled1 = ws + OFF_P1;
    float* h1      = ws + OFF_H1;   // becomes s1 in-place after iaf

    pool0_kernel<<<16384, 256, 0, stream>>>(inp, pooled0);
    conv0_kernel<<<8192, 256, 0, stream>>>(pooled0, w0, h0);
    iaf_kernel<<<512, 256, 0, stream>>>(h0);           // 131,072 positions
    pool1_kernel<<<2048, 256, 0, stream>>>(h0, pooled1);
    conv1_kernel<<<512, 256, 0, stream>>>(pooled1, w1, h1);
    iaf_kernel<<<64, 256, 0, stream>>>(h1);            // 16,384 positions
    final_kernel<<<4, 256, 0, stream>>>(h1, wl, out);
}

// Round 2
// 541.756 us; speedup vs baseline: 1.0992x; 1.0992x over previous
//
#include <hip/hip_runtime.h>

// Problem: ExodusModel_8564164788248
// inp: (8,2,256,256,64) f32, w0: (4,2,7,7), w1: (8,4,7,7), wl: (2,128)
// out: (8,2,64) f32
//
// Workspace layout (floats):
//   pooled0 : (8,2,64,64,64)  = 4,194,304   @ 0
//   h0      : (8,4,64,64,64)  = 8,388,608   @ 4,194,304   (never stores s0!)
//   pooled1 : (8,4,16,16,64)  =   524,288   @ 12,582,912
//   h1/s1   : (8,8,16,16,64)  = 1,048,576   @ 13,107,200

#define OFF_P0   0
#define OFF_H0   4194304
#define OFF_P1   12582912
#define OFF_H1   13107200

// ---------------------------------------------------------------------------
// K1: avgpool 4x4 on raw input. (n,c,256,256,t) -> (n,c,64,64,t)
// 4 t per thread (float4 on the stride-1 axis). fp64 accumulate, same
// (dy,dx) order as round-1 => bit-identical pooled0.
__global__ void pool0_kernel(const float* __restrict__ inp,
                             float* __restrict__ out) {
    int tid = blockIdx.x * blockDim.x + threadIdx.x;   // 1,048,576 threads
    int t4 = tid & 15;
    int px = (tid >> 4) & 63;
    int py = (tid >> 10) & 63;
    int nc = tid >> 16;                                // n*2+c, 0..15
    const float* base = inp + (size_t)nc * 4194304 + (size_t)t4 * 4;
    int y0 = py * 4, x0 = px * 4;
    double a0 = 0, a1 = 0, a2 = 0, a3 = 0;
    #pragma unroll
    for (int dy = 0; dy < 4; ++dy) {
        const float* row = base + ((size_t)(y0 + dy) * 256 + x0) * 64;
        #pragma unroll
        for (int dx = 0; dx < 4; ++dx) {
            const float4 v = *(const float4*)(row + dx * 64);
            a0 += (double)v.x; a1 += (double)v.y;
            a2 += (double)v.z; a3 += (double)v.w;
        }
    }
    float4 o = make_float4((float)(a0 * 0.0625), (float)(a1 * 0.0625),
                           (float)(a2 * 0.0625), (float)(a3 * 0.0625));
    ((float4*)out)[tid] = o;   // flat idx == tid by construction
}

// ---------------------------------------------------------------------------
// K2: conv7 pad3, ic=2 -> oc=4 on (n,2,64,64,t). One thread per
// (n,py,px,t4) computing 4 oc x 4 t. fp64 accumulate, (ic,ky,kx) tap order
// identical to round-1 => bit-identical h0.
__global__ void conv0_kernel(const float* __restrict__ pooled0,
                             const float* __restrict__ w0,
                             float* __restrict__ h0) {
    __shared__ double w[392];                          // (4,2,7,7)
    for (int i = threadIdx.x; i < 392; i += blockDim.x) w[i] = (double)w0[i];
    __syncthreads();

    int tid = blockIdx.x * blockDim.x + threadIdx.x;   // 524,288 threads
    int t4 = tid & 15;
    int px = (tid >> 4) & 63;
    int py = (tid >> 10) & 63;
    int n  = tid >> 16;                                // 0..7
    double acc[4][4] = {};                             // [oc][t]
    for (int ic = 0; ic < 2; ++ic) {
        const float* in_c = pooled0 + (size_t)(n * 2 + ic) * 262144 + t4 * 4;
        const double* wic = w + ic * 49;               // + oc*98 + ky*7 + kx
        #pragma unroll
        for (int ky = 0; ky < 7; ++ky) {
            int iy = py + ky - 3;
            if (iy < 0 || iy >= 64) continue;
            const float* in_row = in_c + (size_t)iy * 4096;
            const double* wrow = wic + ky * 7;
            #pragma unroll
            for (int kx = 0; kx < 7; ++kx) {
                int ix = px + kx - 3;
                if (ix < 0 || ix >= 64) continue;
                float4 v = *(const float4*)(in_row + ix * 64);
                #pragma unroll
                for (int oc = 0; oc < 4; ++oc) {
                    double wd = wrow[kx + oc * 98];
                    acc[oc][0] += (double)v.x * wd;
                    acc[oc][1] += (double)v.y * wd;
                    acc[oc][2] += (double)v.z * wd;
                    acc[oc][3] += (double)v.w * wd;
                }
            }
        }
    }
    size_t ob = (size_t)n * 1048576 + (size_t)py * 4096 + (size_t)px * 64 + t4 * 4;
    #pragma unroll
    for (int oc = 0; oc < 4; ++oc) {
        float4 o = make_float4((float)acc[oc][0], (float)acc[oc][1],
                               (float)acc[oc][2], (float)acc[oc][3]);
        *(float4*)(h0 + ob + (size_t)oc * 262144) = o;
    }
}

// ---------------------------------------------------------------------------
// K3: fused IAF0 + avgpool4. Never materializes s0.
// Block = (n, pyo): covers (4 c, 4 dy, 64 px, 64 t). Thread = (c,dy,pxo):
// scans the 4 dx membrane streams in registers (exact reference fp32
// sequence), accumulates spike sums over dx, reduces over dy via a 64 KB
// rotate-swizzled LDS buffer (conflict-free), writes pooled1.
__global__ void iaf0_pool1_kernel(const float* __restrict__ h0,
                                  float* __restrict__ pooled1) {
    __shared__ float buf[64 * 256];                    // [t][r], r rotated by t

    int b = blockIdx.x;                                // 128 = (n 8)(pyo 16)
    int pyo = b & 15;
    int n   = b >> 4;
    int tid = threadIdx.x;                             // (c 4)(dy 4)(pxo 16)
    int pxo = tid & 15;
    int dy  = (tid >> 4) & 3;
    int c   = tid >> 6;
    int py  = pyo * 4 + dy;

    const float* base = h0 + (((size_t)(n * 4 + c) * 64 + py) * 64 + pxo * 4) * 64;
    const float4* p0 = (const float4*)(base);
    const float4* p1 = (const float4*)(base + 64);
    const float4* p2 = (const float4*)(base + 128);
    const float4* p3 = (const float4*)(base + 192);

    float v0 = 0.f, v1 = 0.f, v2 = 0.f, v3 = 0.f;
    float sg[64];
    #pragma unroll
    for (int i = 0; i < 16; ++i) {
        float4 x0 = p0[i], x1 = p1[i], x2 = p2[i], x3 = p3[i];
        #define STEP(j, e)                                                    \
        {   float s0_, s1_, s2_, s3_;                                         \
            v0 += x0.e; s0_ = (v0 >= 1.f) ? 1.f : 0.f; v0 -= s0_;             \
            v1 += x1.e; s1_ = (v1 >= 1.f) ? 1.f : 0.f; v1 -= s1_;             \
            v2 += x2.e; s2_ = (v2 >= 1.f) ? 1.f : 0.f; v2 -= s2_;             \
            v3 += x3.e; s3_ = (v3 >= 1.f) ? 1.f : 0.f; v3 -= s3_;             \
            sg[i * 4 + j] = (s0_ + s1_) + (s2_ + s3_);  }
        STEP(0, x) STEP(1, y) STEP(2, z) STEP(3, w)
        #undef STEP
    }
    #pragma unroll
    for (int t = 0; t < 64; ++t)
        buf[t * 256 + ((tid + t) & 255)] = sg[t];      // bank = (tid+t)%32: free
    __syncthreads();

    // reduce over dy: 4096 outputs (c,pxo,t) -> 16 per thread
    int t = tid & 63;
    int u = tid >> 6;                                  // 0..3
    #pragma unroll
    for (int k = 0; k < 16; ++k) {
        int combo = k * 4 + u;                         // (c,pxo) in 0..63
        int oc  = combo >> 4;
        int opx = combo & 15;
        float sum = 0.f;
        #pragma unroll
        for (int dy2 = 0; dy2 < 4; ++dy2) {
            int r = oc * 64 + dy2 * 16 + opx;
            sum += buf[t * 256 + ((r + t) & 255)];     // bank = (r+t)%32: free
        }
        pooled1[(((size_t)(n * 4 + oc) * 16 + pyo) * 16 + opx) * 64 + t]
            = sum * 0.0625f;
    }
}

// ---------------------------------------------------------------------------
// K4: conv7 pad3, ic=4 -> oc=8 on (8,4,16,16,t). fp64 accumulate (same tap
// order as round-1).
__global__ void conv1_kernel(const float* __restrict__ pooled1,
                             const float* __restrict__ w1,
                             float* __restrict__ h1) {
    __shared__ double w[1568];                         // (8,4,7,7)
    for (int i = threadIdx.x; i < 1568; i += blockDim.x) w[i] = (double)w1[i];
    __syncthreads();

    int tid = blockIdx.x * blockDim.x + threadIdx.x;   // 131,072 threads
    int t  = tid & 63;
    int px = (tid >> 6) & 15;
    int py = (tid >> 10) & 15;
    int n  = tid >> 14;                                // 0..7
    double acc[8];
    #pragma unroll
    for (int oc = 0; oc < 8; ++oc) acc[oc] = 0.0;

    for (int ic = 0; ic < 4; ++ic) {
        const float* in_c = pooled1 + (size_t)(n * 4 + ic) * 16384;
        const double* wic = w + ic * 49;               // + oc*196 + ky*7 + kx
        #pragma unroll
        for (int ky = 0; ky < 7; ++ky) {
            int iy = py + ky - 3;
            if (iy < 0 || iy >= 16) continue;
            const float* in_row = in_c + (size_t)iy * 1024 + t;
            const double* wrow = wic + ky * 7;
            #pragma unroll
            for (int kx = 0; kx < 7; ++kx) {
                int ix = px + kx - 3;
                if (ix < 0 || ix >= 16) continue;
                double v = (double)in_row[ix * 64];
                #pragma unroll
                for (int oc = 0; oc < 8; ++oc)
                    acc[oc] += v * wrow[kx + oc * 196];
            }
        }
    }
    size_t ob = (size_t)n * 131072 + (size_t)py * 1024 + px * 64 + t;
    #pragma unroll
    for (int oc = 0; oc < 8; ++oc)
        h1[ob + (size_t)oc * 16384] = (float)acc[oc];
}

// ---------------------------------------------------------------------------
// K5: IAF in-place (exact reference fp32 sequence), one thread per position.
__global__ void iaf_kernel(float* __restrict__ buf) {
    int tid = blockIdx.x * blockDim.x + threadIdx.x;
    float4* p = (float4*)(buf + (size_t)tid * 64);
    float v = 0.0f;
    #pragma unroll
    for (int i = 0; i < 16; ++i) {
        float4 x = p[i];
        v += x.x; { float s = (v >= 1.0f) ? 1.0f : 0.0f; v -= s; x.x = s; }
        v += x.y; { float s = (v >= 1.0f) ? 1.0f : 0.0f; v -= s; x.y = s; }
        v += x.z; { float s = (v >= 1.0f) ? 1.0f : 0.0f; v -= s; x.z = s; }
        v += x.w; { float s = (v >= 1.0f) ? 1.0f : 0.0f; v -= s; x.w = s; }
        p[i] = x;
    }
}

// ---------------------------------------------------------------------------
// K6: avgpool4 (16x16 -> 4x4) + flatten(128) + linear (wl: (2,128)).
__global__ void final_kernel(const float* __restrict__ s1,
                             const float* __restrict__ wl,
                             float* __restrict__ out) {
    int tid = blockIdx.x * blockDim.x + threadIdx.x;   // 1024 threads
    int t = tid & 63;
    int j = (tid >> 6) & 1;
    int n = tid >> 7;
    double acc = 0.0;
    for (int c = 0; c < 8; ++c) {
        const float* base = s1 + (size_t)(n * 8 + c) * 16384;
        #pragma unroll
        for (int py = 0; py < 4; ++py) {
            #pragma unroll
            for (int px = 0; px < 4; ++px) {
                float ssum = 0.0f;
                #pragma unroll
                for (int dy = 0; dy < 4; ++dy) {
                    const float* row = base + ((size_t)(py * 4 + dy) * 16 + px * 4) * 64 + t;
                    #pragma unroll
                    for (int dx = 0; dx < 4; ++dx)
                        ssum += row[dx * 64];
                }
                float feat = ssum * 0.0625f;
                acc += (double)wl[j * 128 + c * 16 + py * 4 + px] * (double)feat;
            }
        }
    }
    out[(size_t)(n * 2 + j) * 64 + t] = (float)acc;
}

// ---------------------------------------------------------------------------
extern "C" void kernel_launch(void* const* d_in, const int* in_sizes, int n_in,
                              void* d_out, int out_size, void* d_ws, size_t ws_size,
                              hipStream_t stream) {
    const float* inp = (const float*)d_in[0];
    const float* w0  = (const float*)d_in[1];
    const float* w1  = (const float*)d_in[2];
    const float* wl  = (const float*)d_in[3];
    float* out = (float*)d_out;
    float* ws  = (float*)d_ws;

    float* pooled0 = ws + OFF_P0;
    float* h0      = ws + OFF_H0;
    float* pooled1 = ws + OFF_P1;
    float* h1      = ws + OFF_H1;   // becomes s1 in-place after iaf

    pool0_kernel<<<4096, 256, 0, stream>>>(inp, pooled0);
    conv0_kernel<<<2048, 256, 0, stream>>>(pooled0, w0, h0);
    iaf0_pool1_kernel<<<128, 256, 0, stream>>>(h0, pooled1);
    conv1_kernel<<<512, 256, 0, stream>>>(pooled1, w1, h1);
    iaf_kernel<<<64, 256, 0, stream>>>(h1);            // 16,384 positions
    final_kernel<<<4, 256, 0, stream>>>(h1, wl, out);
}

// Round 3
// 525.569 us; speedup vs baseline: 1.1330x; 1.0308x over previous
//
#include <hip/hip_runtime.h>

// Problem: ExodusModel_8564164788248
// inp: (8,2,256,256,64) f32, w0: (4,2,7,7), w1: (8,4,7,7), wl: (2,128)
// out: (8,2,64) f32
//
// Workspace layout (floats):
//   pooled0 : (8,2,64,64,64)  = 4,194,304   @ 0
//   h0      : (8,4,64,64,64)  = 8,388,608   @ 4,194,304   (s0 never stored)
//   pooled1 : (8,4,16,16,64)  =   524,288   @ 12,582,912
//   h1/s1   : (8,8,16,16,64)  = 1,048,576   @ 13,107,200

#define OFF_P0   0
#define OFF_H0   4194304
#define OFF_P1   12582912
#define OFF_H1   13107200

// ---------------------------------------------------------------------------
// K1: avgpool 4x4 on raw input. (n,c,256,256,t) -> (n,c,64,64,t)
// float4 on stride-1 t axis; fp64 accumulate (exact /16). Memory-floor bound.
__global__ void pool0_kernel(const float* __restrict__ inp,
                             float* __restrict__ out) {
    int tid = blockIdx.x * blockDim.x + threadIdx.x;   // 1,048,576 threads
    int t4 = tid & 15;
    int px = (tid >> 4) & 63;
    int py = (tid >> 10) & 63;
    int nc = tid >> 16;                                // n*2+c, 0..15
    const float* base = inp + (size_t)nc * 4194304 + (size_t)t4 * 4;
    int y0 = py * 4, x0 = px * 4;
    double a0 = 0, a1 = 0, a2 = 0, a3 = 0;
    #pragma unroll
    for (int dy = 0; dy < 4; ++dy) {
        const float* row = base + ((size_t)(y0 + dy) * 256 + x0) * 64;
        #pragma unroll
        for (int dx = 0; dx < 4; ++dx) {
            const float4 v = *(const float4*)(row + dx * 64);
            a0 += (double)v.x; a1 += (double)v.y;
            a2 += (double)v.z; a3 += (double)v.w;
        }
    }
    float4 o = make_float4((float)(a0 * 0.0625), (float)(a1 * 0.0625),
                           (float)(a2 * 0.0625), (float)(a3 * 0.0625));
    ((float4*)out)[tid] = o;
}

// ---------------------------------------------------------------------------
// K2: conv7 pad3, ic=2 -> oc=4. One thread computes 2 adjacent py rows
// (4 oc x 4 t x 2 py), sharing tap loads between the rows (8 input rows
// feed 2 output rows: 112 loads vs 196). Per-output tap order is still
// (ic, ky ascending, kx ascending) => bit-identical h0.
__global__ void conv0_kernel(const float* __restrict__ pooled0,
                             const float* __restrict__ w0,
                             float* __restrict__ h0) {
    __shared__ double w[392];                          // [oc*98 + ic*49 + ky*7 + kx]
    for (int i = threadIdx.x; i < 392; i += blockDim.x) w[i] = (double)w0[i];
    __syncthreads();

    int tid = blockIdx.x * blockDim.x + threadIdx.x;   // 262,144 threads
    int t4  = tid & 15;
    int px  = (tid >> 4) & 63;
    int pyp = (tid >> 10) & 31;
    int n   = tid >> 15;                               // 0..7
    int py0 = pyp * 2;                                 // rows py0, py0+1

    double acc[4][2][4] = {};                          // [oc][p][t]
    for (int ic = 0; ic < 2; ++ic) {
        const float* in_c = pooled0 + (size_t)(n * 2 + ic) * 262144 + t4 * 4;
        const double* wic = w + ic * 49;               // + oc*98 + ky*7 + kx
        #pragma unroll
        for (int r = 0; r < 8; ++r) {                  // iy = py0-3+r
            int iy = py0 - 3 + r;
            if (iy < 0 || iy >= 64) continue;
            const float* in_row = in_c + (size_t)iy * 4096;
            #pragma unroll
            for (int kx = 0; kx < 7; ++kx) {
                int ix = px + kx - 3;
                if (ix < 0 || ix >= 64) continue;
                float4 v = *(const float4*)(in_row + ix * 64);
                if (r <= 6) {                          // ky = r for row py0
                    #pragma unroll
                    for (int oc = 0; oc < 4; ++oc) {
                        double wd = wic[oc * 98 + r * 7 + kx];
                        acc[oc][0][0] += (double)v.x * wd;
                        acc[oc][0][1] += (double)v.y * wd;
                        acc[oc][0][2] += (double)v.z * wd;
                        acc[oc][0][3] += (double)v.w * wd;
                    }
                }
                if (r >= 1) {                          // ky = r-1 for row py0+1
                    #pragma unroll
                    for (int oc = 0; oc < 4; ++oc) {
                        double wd = wic[oc * 98 + (r - 1) * 7 + kx];
                        acc[oc][1][0] += (double)v.x * wd;
                        acc[oc][1][1] += (double)v.y * wd;
                        acc[oc][1][2] += (double)v.z * wd;
                        acc[oc][1][3] += (double)v.w * wd;
                    }
                }
            }
        }
    }
    #pragma unroll
    for (int p = 0; p < 2; ++p) {
        size_t ob = (size_t)n * 1048576 + (size_t)(py0 + p) * 4096
                  + (size_t)px * 64 + t4 * 4;
        #pragma unroll
        for (int oc = 0; oc < 4; ++oc) {
            float4 o = make_float4((float)acc[oc][p][0], (float)acc[oc][p][1],
                                   (float)acc[oc][p][2], (float)acc[oc][p][3]);
            *(float4*)(h0 + ob + (size_t)oc * 262144) = o;
        }
    }
}

// ---------------------------------------------------------------------------
// K3: fused IAF0 + avgpool4, no LDS. 512 single-wave blocks (all CUs busy).
// Thread = (dy, pxo) within wave; block = (n, pyo, c). Each thread scans the
// 4 dx membrane streams (exact reference fp32 sequence), sums spikes over dx
// (exact small ints), then dy-reduces via shfl_xor butterfly (exact, order-
// free) and stores coalesced float4s.
__global__ __launch_bounds__(64) void iaf0_pool1_kernel(
        const float* __restrict__ h0, float* __restrict__ pooled1) {
    int b   = blockIdx.x;                              // 512 = (n 8)(pyo 16)(c 4)
    int c   = b & 3;
    int pyo = (b >> 2) & 15;
    int n   = b >> 6;
    int lane = threadIdx.x;
    int pxo = lane & 15;
    int dy  = lane >> 4;                               // 0..3
    int py  = pyo * 4 + dy;

    const float* base = h0 + (((size_t)(n * 4 + c) * 64 + py) * 64 + pxo * 4) * 64;
    const float4* p0 = (const float4*)(base);
    const float4* p1 = (const float4*)(base + 64);
    const float4* p2 = (const float4*)(base + 128);
    const float4* p3 = (const float4*)(base + 192);

    float v0 = 0.f, v1 = 0.f, v2 = 0.f, v3 = 0.f;
    float sg[64];
    #pragma unroll
    for (int i = 0; i < 16; ++i) {
        float4 x0 = p0[i], x1 = p1[i], x2 = p2[i], x3 = p3[i];
        #define STEP(j, e)                                                    \
        {   float s0_, s1_, s2_, s3_;                                         \
            v0 += x0.e; s0_ = (v0 >= 1.f) ? 1.f : 0.f; v0 -= s0_;             \
            v1 += x1.e; s1_ = (v1 >= 1.f) ? 1.f : 0.f; v1 -= s1_;             \
            v2 += x2.e; s2_ = (v2 >= 1.f) ? 1.f : 0.f; v2 -= s2_;             \
            v3 += x3.e; s3_ = (v3 >= 1.f) ? 1.f : 0.f; v3 -= s3_;             \
            sg[i * 4 + j] = (s0_ + s1_) + (s2_ + s3_);  }
        STEP(0, x) STEP(1, y) STEP(2, z) STEP(3, w)
        #undef STEP
    }
    // dy butterfly: lanes differ in bits 4,5. Spike sums are small integers
    // => exact in fp32 regardless of order.
    #pragma unroll
    for (int j = 0; j < 64; ++j) {
        sg[j] += __shfl_xor(sg[j], 16);
        sg[j] += __shfl_xor(sg[j], 32);
    }
    float* outrow = pooled1 + (((size_t)(n * 4 + c) * 16 + pyo) * 16 + pxo) * 64;
    #pragma unroll
    for (int jj = 0; jj < 4; ++jj) {
        int t0 = dy * 4 + jj * 16;                     // lanes cover 64B segs
        float4 o = make_float4(sg[t0] * 0.0625f, sg[t0 + 1] * 0.0625f,
                               sg[t0 + 2] * 0.0625f, sg[t0 + 3] * 0.0625f);
        *(float4*)(outrow + t0) = o;
    }
}

// ---------------------------------------------------------------------------
// K4: conv7 pad3, ic=4 -> oc=8 on (8,4,16,16,t). fp64 accumulate, same tap
// order as before => bit-identical h1.
__global__ void conv1_kernel(const float* __restrict__ pooled1,
                             const float* __restrict__ w1,
                             float* __restrict__ h1) {
    __shared__ double w[1568];                         // (8,4,7,7)
    for (int i = threadIdx.x; i < 1568; i += blockDim.x) w[i] = (double)w1[i];
    __syncthreads();

    int tid = blockIdx.x * blockDim.x + threadIdx.x;   // 131,072 threads
    int t  = tid & 63;
    int px = (tid >> 6) & 15;
    int py = (tid >> 10) & 15;
    int n  = tid >> 14;                                // 0..7
    double acc[8];
    #pragma unroll
    for (int oc = 0; oc < 8; ++oc) acc[oc] = 0.0;

    for (int ic = 0; ic < 4; ++ic) {
        const float* in_c = pooled1 + (size_t)(n * 4 + ic) * 16384;
        const double* wic = w + ic * 49;               // + oc*196 + ky*7 + kx
        #pragma unroll
        for (int ky = 0; ky < 7; ++ky) {
            int iy = py + ky - 3;
            if (iy < 0 || iy >= 16) continue;
            const float* in_row = in_c + (size_t)iy * 1024 + t;
            const double* wrow = wic + ky * 7;
            #pragma unroll
            for (int kx = 0; kx < 7; ++kx) {
                int ix = px + kx - 3;
                if (ix < 0 || ix >= 16) continue;
                double v = (double)in_row[ix * 64];
                #pragma unroll
                for (int oc = 0; oc < 8; ++oc)
                    acc[oc] += v * wrow[kx + oc * 196];
            }
        }
    }
    size_t ob = (size_t)n * 131072 + (size_t)py * 1024 + px * 64 + t;
    #pragma unroll
    for (int oc = 0; oc < 8; ++oc)
        h1[ob + (size_t)oc * 16384] = (float)acc[oc];
}

// ---------------------------------------------------------------------------
// K5: IAF in-place (exact reference fp32 sequence), one thread per position.
__global__ void iaf_kernel(float* __restrict__ buf) {
    int tid = blockIdx.x * blockDim.x + threadIdx.x;
    float4* p = (float4*)(buf + (size_t)tid * 64);
    float v = 0.0f;
    #pragma unroll
    for (int i = 0; i < 16; ++i) {
        float4 x = p[i];
        v += x.x; { float s = (v >= 1.0f) ? 1.0f : 0.0f; v -= s; x.x = s; }
        v += x.y; { float s = (v >= 1.0f) ? 1.0f : 0.0f; v -= s; x.y = s; }
        v += x.z; { float s = (v >= 1.0f) ? 1.0f : 0.0f; v -= s; x.z = s; }
        v += x.w; { float s = (v >= 1.0f) ? 1.0f : 0.0f; v -= s; x.w = s; }
        p[i] = x;
    }
}

// ---------------------------------------------------------------------------
// K6: avgpool4 (16x16 -> 4x4) + flatten(128) + linear (wl: (2,128)).
__global__ void final_kernel(const float* __restrict__ s1,
                             const float* __restrict__ wl,
                             float* __restrict__ out) {
    int tid = blockIdx.x * blockDim.x + threadIdx.x;   // 1024 threads
    int t = tid & 63;
    int j = (tid >> 6) & 1;
    int n = tid >> 7;
    double acc = 0.0;
    for (int c = 0; c < 8; ++c) {
        const float* base = s1 + (size_t)(n * 8 + c) * 16384;
        #pragma unroll
        for (int py = 0; py < 4; ++py) {
            #pragma unroll
            for (int px = 0; px < 4; ++px) {
                float ssum = 0.0f;
                #pragma unroll
                for (int dy = 0; dy < 4; ++dy) {
                    const float* row = base + ((size_t)(py * 4 + dy) * 16 + px * 4) * 64 + t;
                    #pragma unroll
                    for (int dx = 0; dx < 4; ++dx)
                        ssum += row[dx * 64];
                }
                float feat = ssum * 0.0625f;
                acc += (double)wl[j * 128 + c * 16 + py * 4 + px] * (double)feat;
            }
        }
    }
    out[(size_t)(n * 2 + j) * 64 + t] = (float)acc;
}

// ---------------------------------------------------------------------------
extern "C" void kernel_launch(void* const* d_in, const int* in_sizes, int n_in,
                              void* d_out, int out_size, void* d_ws, size_t ws_size,
                              hipStream_t stream) {
    const float* inp = (const float*)d_in[0];
    const float* w0  = (const float*)d_in[1];
    const float* w1  = (const float*)d_in[2];
    const float* wl  = (const float*)d_in[3];
    float* out = (float*)d_out;
    float* ws  = (float*)d_ws;

    float* pooled0 = ws + OFF_P0;
    float* h0      = ws + OFF_H0;
    float* pooled1 = ws + OFF_P1;
    float* h1      = ws + OFF_H1;   // becomes s1 in-place after iaf

    pool0_kernel<<<4096, 256, 0, stream>>>(inp, pooled0);
    conv0_kernel<<<1024, 256, 0, stream>>>(pooled0, w0, h0);
    iaf0_pool1_kernel<<<512, 64, 0, stream>>>(h0, pooled1);
    conv1_kernel<<<512, 256, 0, stream>>>(pooled1, w1, h1);
    iaf_kernel<<<64, 256, 0, stream>>>(h1);            // 16,384 positions
    final_kernel<<<4, 256, 0, stream>>>(h1, wl, out);
}

// Round 4
// 477.281 us; speedup vs baseline: 1.2477x; 1.1012x over previous
//
#include <hip/hip_runtime.h>

// Problem: ExodusModel_8564164788248
// inp: (8,2,256,256,64) f32, w0: (4,2,7,7), w1: (8,4,7,7), wl: (2,128)
// out: (8,2,64) f32
//
// Workspace layout (floats):
//   pooled0 : (8,2,64,64,64)  = 4,194,304   @ 0
//   h0      : (8,4,64,64,64)  = 8,388,608   @ 4,194,304   (s0 never stored)
//   pooled1 : (8,4,16,16,64)  =   524,288   @ 12,582,912
//   h1      : (8,8,16,16,64)  = 1,048,576   @ 13,107,200  (s1 never stored)
//   feat    : (8,128,64)      =    65,536   @ 14,155,776

#define OFF_P0   0
#define OFF_H0   4194304
#define OFF_P1   12582912
#define OFF_H1   13107200
#define OFF_FT   14155776

// ---------------------------------------------------------------------------
// K1: avgpool 4x4 on raw input. (n,c,256,256,t) -> (n,c,64,64,t)
// float4 on stride-1 t axis; fp64 accumulate (exact /16). HBM-floor bound.
__global__ void pool0_kernel(const float* __restrict__ inp,
                             float* __restrict__ out) {
    int tid = blockIdx.x * blockDim.x + threadIdx.x;   // 1,048,576 threads
    int t4 = tid & 15;
    int px = (tid >> 4) & 63;
    int py = (tid >> 10) & 63;
    int nc = tid >> 16;                                // n*2+c, 0..15
    const float* base = inp + (size_t)nc * 4194304 + (size_t)t4 * 4;
    int y0 = py * 4, x0 = px * 4;
    double a0 = 0, a1 = 0, a2 = 0, a3 = 0;
    #pragma unroll
    for (int dy = 0; dy < 4; ++dy) {
        const float* row = base + ((size_t)(y0 + dy) * 256 + x0) * 64;
        #pragma unroll
        for (int dx = 0; dx < 4; ++dx) {
            const float4 v = *(const float4*)(row + dx * 64);
            a0 += (double)v.x; a1 += (double)v.y;
            a2 += (double)v.z; a3 += (double)v.w;
        }
    }
    float4 o = make_float4((float)(a0 * 0.0625), (float)(a1 * 0.0625),
                           (float)(a2 * 0.0625), (float)(a3 * 0.0625));
    ((float4*)out)[tid] = o;
}

// ---------------------------------------------------------------------------
// K2: conv7 pad3, ic=2 -> oc=4. One thread computes 2 adjacent py rows
// (4 oc x 4 t x 2 py), sharing tap loads. Per-output tap order is
// (ic, ky, kx) ascending => bit-identical h0. fp64-FMA-pipe bound (~21 us).
__global__ void conv0_kernel(const float* __restrict__ pooled0,
                             const float* __restrict__ w0,
                             float* __restrict__ h0) {
    __shared__ double w[392];                          // [oc*98 + ic*49 + ky*7 + kx]
    for (int i = threadIdx.x; i < 392; i += blockDim.x) w[i] = (double)w0[i];
    __syncthreads();

    int tid = blockIdx.x * blockDim.x + threadIdx.x;   // 262,144 threads
    int t4  = tid & 15;
    int px  = (tid >> 4) & 63;
    int pyp = (tid >> 10) & 31;
    int n   = tid >> 15;                               // 0..7
    int py0 = pyp * 2;                                 // rows py0, py0+1

    double acc[4][2][4] = {};                          // [oc][p][t]
    for (int ic = 0; ic < 2; ++ic) {
        const float* in_c = pooled0 + (size_t)(n * 2 + ic) * 262144 + t4 * 4;
        const double* wic = w + ic * 49;               // + oc*98 + ky*7 + kx
        #pragma unroll
        for (int r = 0; r < 8; ++r) {                  // iy = py0-3+r
            int iy = py0 - 3 + r;
            if (iy < 0 || iy >= 64) continue;
            const float* in_row = in_c + (size_t)iy * 4096;
            #pragma unroll
            for (int kx = 0; kx < 7; ++kx) {
                int ix = px + kx - 3;
                if (ix < 0 || ix >= 64) continue;
                float4 v = *(const float4*)(in_row + ix * 64);
                if (r <= 6) {                          // ky = r for row py0
                    #pragma unroll
                    for (int oc = 0; oc < 4; ++oc) {
                        double wd = wic[oc * 98 + r * 7 + kx];
                        acc[oc][0][0] += (double)v.x * wd;
                        acc[oc][0][1] += (double)v.y * wd;
                        acc[oc][0][2] += (double)v.z * wd;
                        acc[oc][0][3] += (double)v.w * wd;
                    }
                }
                if (r >= 1) {                          // ky = r-1 for row py0+1
                    #pragma unroll
                    for (int oc = 0; oc < 4; ++oc) {
                        double wd = wic[oc * 98 + (r - 1) * 7 + kx];
                        acc[oc][1][0] += (double)v.x * wd;
                        acc[oc][1][1] += (double)v.y * wd;
                        acc[oc][1][2] += (double)v.z * wd;
                        acc[oc][1][3] += (double)v.w * wd;
                    }
                }
            }
        }
    }
    #pragma unroll
    for (int p = 0; p < 2; ++p) {
        size_t ob = (size_t)n * 1048576 + (size_t)(py0 + p) * 4096
                  + (size_t)px * 64 + t4 * 4;
        #pragma unroll
        for (int oc = 0; oc < 4; ++oc) {
            float4 o = make_float4((float)acc[oc][p][0], (float)acc[oc][p][1],
                                   (float)acc[oc][p][2], (float)acc[oc][p][3]);
            *(float4*)(h0 + ob + (size_t)oc * 262144) = o;
        }
    }
}

// ---------------------------------------------------------------------------
// K3: fused IAF0 + avgpool4, no LDS, 512x256 (8 waves/CU). One membrane
// stream per thread (exact reference fp32 sequence); spike bits byte-packed
// 4-per-u32 (pool sums <=16 fit a byte => exact integer adds); dx/dy
// reduction via shfl_xor(1,2,4,8); coalesced 1KB/wave float4 stores.
__global__ __launch_bounds__(256) void iaf0_pool1_kernel(
        const float* __restrict__ h0, float* __restrict__ pooled1) {
    int b   = blockIdx.x;                              // 512 = (n 8)(pyo 16)(c 4)
    int c   = b & 3;
    int pyo = (b >> 2) & 15;
    int n   = b >> 6;
    int tid = threadIdx.x;                             // dx(2b) dy(2b) pxo(4b)
    int dx  = tid & 3;
    int dy  = (tid >> 2) & 3;
    int pxo = tid >> 4;                                // 0..15
    int py  = pyo * 4 + dy;
    int px  = pxo * 4 + dx;

    const float4* p = (const float4*)(h0 +
        (((size_t)(n * 4 + c) * 64 + py) * 64 + px) * 64);

    float v = 0.f;
    unsigned int sp[16];
    #pragma unroll
    for (int i = 0; i < 16; ++i) {
        float4 x = p[i];
        unsigned int w = 0;
        #define STEP(j, e)                                                    \
        {   v += x.e;                                                         \
            unsigned int s_ = (v >= 1.f) ? 1u : 0u;                           \
            v -= (float)s_;                                                   \
            w += s_ << (8 * j); }
        STEP(0, x) STEP(1, y) STEP(2, z) STEP(3, w)
        #undef STEP
        sp[i] = w;
    }
    // reduce over dx (lane bits 0,1) and dy (lane bits 2,3); bytes can't carry
    #pragma unroll
    for (int i = 0; i < 16; ++i) {
        sp[i] += __shfl_xor(sp[i], 1);
        sp[i] += __shfl_xor(sp[i], 2);
        sp[i] += __shfl_xor(sp[i], 4);
        sp[i] += __shfl_xor(sp[i], 8);
    }
    // 16-lane group (same pxo) all hold the pooled sums; lane i writes t=4i..4i+3
    int i = tid & 15;
    unsigned int s = sp[i];
    float4 o = make_float4((float)(s & 255u)         * 0.0625f,
                           (float)((s >> 8)  & 255u) * 0.0625f,
                           (float)((s >> 16) & 255u) * 0.0625f,
                           (float)((s >> 24) & 255u) * 0.0625f);
    float* outp = pooled1 + (((size_t)(n * 4 + c) * 16 + pyo) * 16 + pxo) * 64 + i * 4;
    *(float4*)outp = o;
}

// ---------------------------------------------------------------------------
// K4: conv7 pad3, ic=4 -> oc=8 on (8,4,16,16,t). fp64 accumulate, same tap
// order as before => bit-identical h1.
__global__ void conv1_kernel(const float* __restrict__ pooled1,
                             const float* __restrict__ w1,
                             float* __restrict__ h1) {
    __shared__ double w[1568];                         // (8,4,7,7)
    for (int i = threadIdx.x; i < 1568; i += blockDim.x) w[i] = (double)w1[i];
    __syncthreads();

    int tid = blockIdx.x * blockDim.x + threadIdx.x;   // 131,072 threads
    int t  = tid & 63;
    int px = (tid >> 6) & 15;
    int py = (tid >> 10) & 15;
    int n  = tid >> 14;                                // 0..7
    double acc[8];
    #pragma unroll
    for (int oc = 0; oc < 8; ++oc) acc[oc] = 0.0;

    for (int ic = 0; ic < 4; ++ic) {
        const float* in_c = pooled1 + (size_t)(n * 4 + ic) * 16384;
        const double* wic = w + ic * 49;               // + oc*196 + ky*7 + kx
        #pragma unroll
        for (int ky = 0; ky < 7; ++ky) {
            int iy = py + ky - 3;
            if (iy < 0 || iy >= 16) continue;
            const float* in_row = in_c + (size_t)iy * 1024 + t;
            const double* wrow = wic + ky * 7;
            #pragma unroll
            for (int kx = 0; kx < 7; ++kx) {
                int ix = px + kx - 3;
                if (ix < 0 || ix >= 16) continue;
                double v = (double)in_row[ix * 64];
                #pragma unroll
                for (int oc = 0; oc < 8; ++oc)
                    acc[oc] += v * wrow[kx + oc * 196];
            }
        }
    }
    size_t ob = (size_t)n * 131072 + (size_t)py * 1024 + px * 64 + t;
    #pragma unroll
    for (int oc = 0; oc < 8; ++oc)
        h1[ob + (size_t)oc * 16384] = (float)acc[oc];
}

// ---------------------------------------------------------------------------
// K5: fused IAF1 + avgpool4 -> feat(n,128,t). Spikes never hit memory.
// Block = (n 8)(c 8), 256 threads = dx(2b) dy(2b) q(4b) where q=pyo*4+pxo.
// Same byte-pack + shfl_xor reduction as K3. feature index f = c*16 + q.
__global__ __launch_bounds__(256) void iaf1_pool2_kernel(
        const float* __restrict__ h1, float* __restrict__ feat) {
    int b = blockIdx.x;                                // 64 = (n 8)(c 8)
    int c = b & 7;
    int n = b >> 3;
    int tid = threadIdx.x;
    int dx  = tid & 3;
    int dy  = (tid >> 2) & 3;
    int q   = tid >> 4;                                // 0..15 = pyo*4+pxo
    int pyo = q >> 2;
    int pxo = q & 3;
    int py  = pyo * 4 + dy;
    int px  = pxo * 4 + dx;

    const float4* p = (const float4*)(h1 +
        (((size_t)(n * 8 + c) * 16 + py) * 16 + px) * 64);

    float v = 0.f;
    unsigned int sp[16];
    #pragma unroll
    for (int i = 0; i < 16; ++i) {
        float4 x = p[i];
        unsigned int w = 0;
        #define STEP(j, e)                                                    \
        {   v += x.e;                                                         \
            unsigned int s_ = (v >= 1.f) ? 1u : 0u;                           \
            v -= (float)s_;                                                   \
            w += s_ << (8 * j); }
        STEP(0, x) STEP(1, y) STEP(2, z) STEP(3, w)
        #undef STEP
        sp[i] = w;
    }
    #pragma unroll
    for (int i = 0; i < 16; ++i) {
        sp[i] += __shfl_xor(sp[i], 1);
        sp[i] += __shfl_xor(sp[i], 2);
        sp[i] += __shfl_xor(sp[i], 4);
        sp[i] += __shfl_xor(sp[i], 8);
    }
    int i = tid & 15;
    unsigned int s = sp[i];
    float4 o = make_float4((float)(s & 255u)         * 0.0625f,
                           (float)((s >> 8)  & 255u) * 0.0625f,
                           (float)((s >> 16) & 255u) * 0.0625f,
                           (float)((s >> 24) & 255u) * 0.0625f);
    int f = c * 16 + q;
    *(float4*)(feat + ((size_t)n * 128 + f) * 64 + i * 4) = o;
}

// ---------------------------------------------------------------------------
// K6: linear. out(n,j,t) = sum_f wl[j,f] * feat[n,f,t], fp64 acc, f ascending
// (same order as the previous final_kernel => bit-identical out).
__global__ __launch_bounds__(64) void linear_kernel(
        const float* __restrict__ feat, const float* __restrict__ wl,
        float* __restrict__ out) {
    int tid = blockIdx.x * 64 + threadIdx.x;           // 1024 threads
    int t = tid & 63;
    int j = (tid >> 6) & 1;
    int n = tid >> 7;
    const float* fp = feat + (size_t)n * 128 * 64 + t;
    const float* wp = wl + j * 128;
    double acc = 0.0;
    for (int f = 0; f < 128; ++f)
        acc += (double)wp[f] * (double)fp[(size_t)f * 64];
    out[(size_t)(n * 2 + j) * 64 + t] = (float)acc;
}

// ---------------------------------------------------------------------------
extern "C" void kernel_launch(void* const* d_in, const int* in_sizes, int n_in,
                              void* d_out, int out_size, void* d_ws, size_t ws_size,
                              hipStream_t stream) {
    const float* inp = (const float*)d_in[0];
    const float* w0  = (const float*)d_in[1];
    const float* w1  = (const float*)d_in[2];
    const float* wl  = (const float*)d_in[3];
    float* out = (float*)d_out;
    float* ws  = (float*)d_ws;

    float* pooled0 = ws + OFF_P0;
    float* h0      = ws + OFF_H0;
    float* pooled1 = ws + OFF_P1;
    float* h1      = ws + OFF_H1;
    float* feat    = ws + OFF_FT;

    pool0_kernel<<<4096, 256, 0, stream>>>(inp, pooled0);
    conv0_kernel<<<1024, 256, 0, stream>>>(pooled0, w0, h0);
    iaf0_pool1_kernel<<<512, 256, 0, stream>>>(h0, pooled1);
    conv1_kernel<<<512, 256, 0, stream>>>(pooled1, w1, h1);
    iaf1_pool2_kernel<<<64, 256, 0, stream>>>(h1, feat);
    linear_kernel<<<16, 64, 0, stream>>>(feat, wl, out);
}

// Round 5
// 466.478 us; speedup vs baseline: 1.2766x; 1.0232x over previous
//
#include <hip/hip_runtime.h>

// Problem: ExodusModel_8564164788248
// inp: (8,2,256,256,64) f32, w0: (4,2,7,7), w1: (8,4,7,7), wl: (2,128)
// out: (8,2,64) f32
//
// Workspace layout (floats):
//   pooled0 : (8,2,64,64,64)  = 4,194,304   @ 0
//   pooled1 : (8,4,16,16,64)  =   524,288   @ 12,582,912
//   h1      : (8,8,16,16,64)  = 1,048,576   @ 13,107,200  (s1 never stored)
//   feat    : (8,128,64)      =    65,536   @ 14,155,776
//   (h0 is never materialized: conv0 -> IAF0 -> pool1 is fused via LDS)

#define OFF_P0   0
#define OFF_P1   12582912
#define OFF_H1   13107200
#define OFF_FT   14155776

// ---------------------------------------------------------------------------
// K1: avgpool 4x4 on raw input. (n,c,256,256,t) -> (n,c,64,64,t)
// float4 on stride-1 t axis; fp64 accumulate (exact /16). HBM-floor bound.
__global__ void pool0_kernel(const float* __restrict__ inp,
                             float* __restrict__ out) {
    int tid = blockIdx.x * blockDim.x + threadIdx.x;   // 1,048,576 threads
    int t4 = tid & 15;
    int px = (tid >> 4) & 63;
    int py = (tid >> 10) & 63;
    int nc = tid >> 16;                                // n*2+c, 0..15
    const float* base = inp + (size_t)nc * 4194304 + (size_t)t4 * 4;
    int y0 = py * 4, x0 = px * 4;
    double a0 = 0, a1 = 0, a2 = 0, a3 = 0;
    #pragma unroll
    for (int dy = 0; dy < 4; ++dy) {
        const float* row = base + ((size_t)(y0 + dy) * 256 + x0) * 64;
        #pragma unroll
        for (int dx = 0; dx < 4; ++dx) {
            const float4 v = *(const float4*)(row + dx * 64);
            a0 += (double)v.x; a1 += (double)v.y;
            a2 += (double)v.z; a3 += (double)v.w;
        }
    }
    float4 o = make_float4((float)(a0 * 0.0625), (float)(a1 * 0.0625),
                           (float)(a2 * 0.0625), (float)(a3 * 0.0625));
    ((float4*)out)[tid] = o;
}

// ---------------------------------------------------------------------------
// K2: FUSED conv0 + IAF0 + pool1. h0 never hits HBM.
// Grid = (n 8)(pyo 16)(pxb 8) = 1024 blocks x 256 threads, 32 KB LDS.
// Tile: oc 0..3, py = pyo*4..+3, px = pxb*8..+7, t 0..63.
//
// Phase 1 (conv): thread = t4(16) x pxl(8) x pp(2); computes 2 adjacent py
// rows x 4 oc x 4 t, fp64 acc, per-output tap order (ic,ky,kx) ascending ==
// previous conv0 => bit-identical h0 values. Results go to LDS with a
// (t+p)&63 rotation: bank=(t+p)&31 => 2-way (free) in both phases.
// Phase 2 (IAF+pool): 128 threads scan their stream (exact reference fp32
// sequence), byte-pack spikes 4/u32 (sums<=16 fit a byte), shfl_xor(1,2,8,16)
// over (dx,dy), coalesced float4 stores of pooled1.
__global__ __launch_bounds__(256) void conv0_iaf0_pool1_kernel(
        const float* __restrict__ pooled0, const float* __restrict__ w0,
        float* __restrict__ pooled1) {
    __shared__ double w[392];                          // [oc*98 + ic*49 + ky*7 + kx]
    __shared__ float tile[8192];                       // [p 128][t 64], t rotated by p

    for (int i = threadIdx.x; i < 392; i += blockDim.x) w[i] = (double)w0[i];

    int b   = blockIdx.x;                              // (n 8)(pyo 16)(pxb 8)
    int pxb = b & 7;
    int pyo = (b >> 3) & 15;
    int n   = b >> 7;

    int tid = threadIdx.x;
    int t4  = tid & 15;
    int pxl = (tid >> 4) & 7;
    int pp  = tid >> 7;                                // 0..1
    int px  = pxb * 8 + pxl;
    int py0 = pyo * 4 + pp * 2;                        // rows py0, py0+1

    __syncthreads();                                   // weights ready

    double acc[4][2][4] = {};                          // [oc][row][t]
    for (int ic = 0; ic < 2; ++ic) {
        const float* in_c = pooled0 + (size_t)(n * 2 + ic) * 262144 + t4 * 4;
        const double* wic = w + ic * 49;               // + oc*98 + ky*7 + kx
        #pragma unroll
        for (int r = 0; r < 8; ++r) {                  // iy = py0-3+r
            int iy = py0 - 3 + r;
            if (iy < 0 || iy >= 64) continue;
            const float* in_row = in_c + (size_t)iy * 4096;
            #pragma unroll
            for (int kx = 0; kx < 7; ++kx) {
                int ix = px + kx - 3;
                if (ix < 0 || ix >= 64) continue;
                float4 v = *(const float4*)(in_row + ix * 64);
                if (r <= 6) {                          // ky = r for row py0
                    #pragma unroll
                    for (int oc = 0; oc < 4; ++oc) {
                        double wd = wic[oc * 98 + r * 7 + kx];
                        acc[oc][0][0] += (double)v.x * wd;
                        acc[oc][0][1] += (double)v.y * wd;
                        acc[oc][0][2] += (double)v.z * wd;
                        acc[oc][0][3] += (double)v.w * wd;
                    }
                }
                if (r >= 1) {                          // ky = r-1 for row py0+1
                    #pragma unroll
                    for (int oc = 0; oc < 4; ++oc) {
                        double wd = wic[oc * 98 + (r - 1) * 7 + kx];
                        acc[oc][1][0] += (double)v.x * wd;
                        acc[oc][1][1] += (double)v.y * wd;
                        acc[oc][1][2] += (double)v.z * wd;
                        acc[oc][1][3] += (double)v.w * wd;
                    }
                }
            }
        }
    }
    // scatter to LDS, rotated: idx = p*64 + (t+p)&63
    #pragma unroll
    for (int oc = 0; oc < 4; ++oc) {
        #pragma unroll
        for (int row = 0; row < 2; ++row) {
            int p = oc * 32 + (pp * 2 + row) * 8 + pxl;
            #pragma unroll
            for (int j = 0; j < 4; ++j) {
                int tt = t4 * 4 + j;
                tile[p * 64 + ((tt + p) & 63)] = (float)acc[oc][row][j];
            }
        }
    }
    __syncthreads();

    if (tid < 128) {
        int p   = tid;                                 // oc(2b at 5)|pyl(2b at 3)|pxl(3b)
        int oc  = p >> 5;
        int pxo = (p >> 2) & 1;
        float v = 0.f;
        unsigned int sp[16];
        const float* tp = tile + p * 64;
        #pragma unroll
        for (int i = 0; i < 16; ++i) {
            unsigned int wd = 0;
            #pragma unroll
            for (int j = 0; j < 4; ++j) {
                int t = i * 4 + j;
                float x = tp[(t + p) & 63];
                v += x;
                unsigned int s_ = (v >= 1.f) ? 1u : 0u;
                v -= (float)s_;
                wd += s_ << (8 * j);
            }
            sp[i] = wd;
        }
        // pool over dx (bits 0,1) and dy (bits 3,4); bytes can't carry
        #pragma unroll
        for (int i = 0; i < 16; ++i) {
            sp[i] += __shfl_xor(sp[i], 1);
            sp[i] += __shfl_xor(sp[i], 2);
            sp[i] += __shfl_xor(sp[i], 8);
            sp[i] += __shfl_xor(sp[i], 16);
        }
        int i = (p & 3) | (((p >> 3) & 3) << 2);       // member index 0..15
        unsigned int s = sp[i];
        float4 o = make_float4((float)(s & 255u)         * 0.0625f,
                               (float)((s >> 8)  & 255u) * 0.0625f,
                               (float)((s >> 16) & 255u) * 0.0625f,
                               (float)((s >> 24) & 255u) * 0.0625f);
        float* outp = pooled1 +
            (((size_t)(n * 4 + oc) * 16 + pyo) * 16 + (pxb * 2 + pxo)) * 64 + i * 4;
        *(float4*)outp = o;
    }
}

// ---------------------------------------------------------------------------
// K3: conv7 pad3, ic=4 -> oc=8 on (8,4,16,16,t). fp64 accumulate, same tap
// order as before => bit-identical h1.
__global__ void conv1_kernel(const float* __restrict__ pooled1,
                             const float* __restrict__ w1,
                             float* __restrict__ h1) {
    __shared__ double w[1568];                         // (8,4,7,7)
    for (int i = threadIdx.x; i < 1568; i += blockDim.x) w[i] = (double)w1[i];
    __syncthreads();

    int tid = blockIdx.x * blockDim.x + threadIdx.x;   // 131,072 threads
    int t  = tid & 63;
    int px = (tid >> 6) & 15;
    int py = (tid >> 10) & 15;
    int n  = tid >> 14;                                // 0..7
    double acc[8];
    #pragma unroll
    for (int oc = 0; oc < 8; ++oc) acc[oc] = 0.0;

    for (int ic = 0; ic < 4; ++ic) {
        const float* in_c = pooled1 + (size_t)(n * 4 + ic) * 16384;
        const double* wic = w + ic * 49;               // + oc*196 + ky*7 + kx
        #pragma unroll
        for (int ky = 0; ky < 7; ++ky) {
            int iy = py + ky - 3;
            if (iy < 0 || iy >= 16) continue;
            const float* in_row = in_c + (size_t)iy * 1024 + t;
            const double* wrow = wic + ky * 7;
            #pragma unroll
            for (int kx = 0; kx < 7; ++kx) {
                int ix = px + kx - 3;
                if (ix < 0 || ix >= 16) continue;
                double v = (double)in_row[ix * 64];
                #pragma unroll
                for (int oc = 0; oc < 8; ++oc)
                    acc[oc] += v * wrow[kx + oc * 196];
            }
        }
    }
    size_t ob = (size_t)n * 131072 + (size_t)py * 1024 + px * 64 + t;
    #pragma unroll
    for (int oc = 0; oc < 8; ++oc)
        h1[ob + (size_t)oc * 16384] = (float)acc[oc];
}

// ---------------------------------------------------------------------------
// K4: fused IAF1 + avgpool4 -> feat(n,128,t). Spikes never hit memory.
__global__ __launch_bounds__(256) void iaf1_pool2_kernel(
        const float* __restrict__ h1, float* __restrict__ feat) {
    int b = blockIdx.x;                                // 64 = (n 8)(c 8)
    int c = b & 7;
    int n = b >> 3;
    int tid = threadIdx.x;
    int dx  = tid & 3;
    int dy  = (tid >> 2) & 3;
    int q   = tid >> 4;                                // 0..15 = pyo*4+pxo
    int pyo = q >> 2;
    int pxo = q & 3;
    int py  = pyo * 4 + dy;
    int px  = pxo * 4 + dx;

    const float4* p = (const float4*)(h1 +
        (((size_t)(n * 8 + c) * 16 + py) * 16 + px) * 64);

    float v = 0.f;
    unsigned int sp[16];
    #pragma unroll
    for (int i = 0; i < 16; ++i) {
        float4 x = p[i];
        unsigned int w = 0;
        #define STEP(j, e)                                                    \
        {   v += x.e;                                                         \
            unsigned int s_ = (v >= 1.f) ? 1u : 0u;                           \
            v -= (float)s_;                                                   \
            w += s_ << (8 * j); }
        STEP(0, x) STEP(1, y) STEP(2, z) STEP(3, w)
        #undef STEP
        sp[i] = w;
    }
    #pragma unroll
    for (int i = 0; i < 16; ++i) {
        sp[i] += __shfl_xor(sp[i], 1);
        sp[i] += __shfl_xor(sp[i], 2);
        sp[i] += __shfl_xor(sp[i], 4);
        sp[i] += __shfl_xor(sp[i], 8);
    }
    int i = tid & 15;
    unsigned int s = sp[i];
    float4 o = make_float4((float)(s & 255u)         * 0.0625f,
                           (float)((s >> 8)  & 255u) * 0.0625f,
                           (float)((s >> 16) & 255u) * 0.0625f,
                           (float)((s >> 24) & 255u) * 0.0625f);
    int f = c * 16 + q;
    *(float4*)(feat + ((size_t)n * 128 + f) * 64 + i * 4) = o;
}

// ---------------------------------------------------------------------------
// K5: linear. out(n,j,t) = sum_f wl[j,f] * feat[n,f,t], fp64 acc, f ascending
// => bit-identical out.
__global__ __launch_bounds__(64) void linear_kernel(
        const float* __restrict__ feat, const float* __restrict__ wl,
        float* __restrict__ out) {
    int tid = blockIdx.x * 64 + threadIdx.x;           // 1024 threads
    int t = tid & 63;
    int j = (tid >> 6) & 1;
    int n = tid >> 7;
    const float* fp = feat + (size_t)n * 128 * 64 + t;
    const float* wp = wl + j * 128;
    double acc = 0.0;
    for (int f = 0; f < 128; ++f)
        acc += (double)wp[f] * (double)fp[(size_t)f * 64];
    out[(size_t)(n * 2 + j) * 64 + t] = (float)acc;
}

// ---------------------------------------------------------------------------
extern "C" void kernel_launch(void* const* d_in, const int* in_sizes, int n_in,
                              void* d_out, int out_size, void* d_ws, size_t ws_size,
                              hipStream_t stream) {
    const float* inp = (const float*)d_in[0];
    const float* w0  = (const float*)d_in[1];
    const float* w1  = (const float*)d_in[2];
    const float* wl  = (const float*)d_in[3];
    float* out = (float*)d_out;
    float* ws  = (float*)d_ws;

    float* pooled0 = ws + OFF_P0;
    float* pooled1 = ws + OFF_P1;
    float* h1      = ws + OFF_H1;
    float* feat    = ws + OFF_FT;

    pool0_kernel<<<4096, 256, 0, stream>>>(inp, pooled0);
    conv0_iaf0_pool1_kernel<<<1024, 256, 0, stream>>>(pooled0, w0, pooled1);
    conv1_kernel<<<512, 256, 0, stream>>>(pooled1, w1, h1);
    iaf1_pool2_kernel<<<64, 256, 0, stream>>>(h1, feat);
    linear_kernel<<<16, 64, 0, stream>>>(feat, wl, out);
}